// Round 8
// baseline (30.890 us; speedup 1.0000x reference)
//
#include <hip/hip_runtime.h>
#include <hip/hip_bf16.h>

// StreamingConv == GEMM: C[b,o] = sum_k A[b,k]*W[o,k]; A[256][16384], W[1024][16384] f32.
// R8: R7 proved prefetch depth is NOT the limiter (2->3 deep = exactly 0 delta).
// New theory: 1 block/CU (LDS 144KB) means all waves share one barrier -> no TLP;
// f32-in-LDS doubles LDS read bytes + converts redundantly (A x2, B x4 per wave).
// Fix: bf16-in-LDS (reg-stage, cvt once at staging, padded rows LDA=40 ushorts=80B
// -> ~2-way bank conflicts = free), dbuf = 60KB -> TWO blocks/CU. Grid 512 =
// NB(8) x SKB(64), 512 threads. Plain __syncthreads; block-level TLP hides stalls.
// Kept: XCD co-scheduling (wgid%8==kb%8), bf16 partial slices + permuted epilogue.

#define CO    1024
#define KTOT  16384
#define BM    256
#define BN    128
#define NB    8
#define SKB   64
#define KC    (KTOT / SKB)        // 256
#define BK    32                  // k-step; bf16 row data 64B
#define KITERS (KC / BK)          // 8
#define LDA   40                  // ushort stride per LDS row (80B, padded)
#define SLICE_ELEMS (BM * CO)     // 262144 bf16 per slice

typedef __attribute__((ext_vector_type(8))) short short8;
typedef __attribute__((ext_vector_type(4))) float f32x4;
typedef __attribute__((ext_vector_type(4))) unsigned short u16x4;

__device__ __forceinline__ unsigned short f2bf(float f) {
    union { __bf16 h; unsigned short u; } c; c.h = (__bf16)f; return c.u;
}

__device__ __forceinline__ short8 pack8(f32x4 a, f32x4 b) {
    short8 r;
    r[0] = (short)f2bf(a[0]); r[1] = (short)f2bf(a[1]);
    r[2] = (short)f2bf(a[2]); r[3] = (short)f2bf(a[3]);
    r[4] = (short)f2bf(b[0]); r[5] = (short)f2bf(b[1]);
    r[6] = (short)f2bf(b[2]); r[7] = (short)f2bf(b[3]);
    return r;
}

template <bool USE_WS>
__global__ __launch_bounds__(512, 4)
void sconv_gemm_v8(const float* __restrict__ A, const float* __restrict__ W,
                   float* __restrict__ out, unsigned short* __restrict__ wsb) {
    __shared__ __align__(16) unsigned short lA[2][BM * LDA];   // 2 x 20 KB
    __shared__ __align__(16) unsigned short lB[2][BN * LDA];   // 2 x 10 KB  (60 KB tot)

    const int tid  = threadIdx.x;
    const int wid  = tid >> 6;
    const int lane = tid & 63;

    // decode (kb, nb) so wgid%8 == kb%8 (blocks sharing an A k-chunk -> same XCD L2)
    const int wgid = blockIdx.x;
    const int c  = wgid & 7;
    const int rs = wgid >> 3;          // 0..63
    const int nb = rs & 7;
    const int kb = (rs >> 3) * 8 + c;  // 0..63
    const int bn = nb * BN;
    const int k0 = kb * KC;

    // ---- staging map: 16B bf16 units. A: 1024 units (2/thread), B: 512 (1/thread).
    // unit u -> row = u>>2, group g = u&3; source = 8 consecutive f32 at k = g*8.
    const int aR = tid >> 2, aG = tid & 3;         // A unit0: row aR; unit1: row aR+128
    const int bR = tid >> 2, bG = tid & 3;         // B rows 0..127
    const float* Ap0 = A + (size_t)aR * KTOT + k0 + aG * 8;
    const float* Ap1 = Ap0 + (size_t)128 * KTOT;
    const float* Bp  = W + (size_t)(bn + bR) * KTOT + k0 + bG * 8;
    const int wA0 = aR * LDA + aG * 8;
    const int wA1 = wA0 + 128 * LDA;
    const int wB  = bR * LDA + bG * 8;

#define STAGE(BUF, T) {                                                       \
        f32x4 a00 = *(const f32x4*)(Ap0 + (T) * BK);                          \
        f32x4 a01 = *(const f32x4*)(Ap0 + (T) * BK + 4);                      \
        f32x4 a10 = *(const f32x4*)(Ap1 + (T) * BK);                          \
        f32x4 a11 = *(const f32x4*)(Ap1 + (T) * BK + 4);                      \
        f32x4 b0  = *(const f32x4*)(Bp  + (T) * BK);                          \
        f32x4 b1  = *(const f32x4*)(Bp  + (T) * BK + 4);                      \
        *(short8*)&lA[BUF][wA0] = pack8(a00, a01);                            \
        *(short8*)&lA[BUF][wA1] = pack8(a10, a11);                            \
        *(short8*)&lB[BUF][wB]  = pack8(b0, b1);                              \
    }

    // ---- wave -> 64x64 sub-tile (4m x 2n wave grid over 256x128) ----
    const int wm = (wid >> 1) * 64;
    const int wn = (wid & 1) * 64;
    const int q  = lane >> 4;          // k-group (16B) of this lane
    const int fr = lane & 15;

    int offA[4], offB[4];
    #pragma unroll
    for (int mi = 0; mi < 4; ++mi) offA[mi] = (wm + mi * 16 + fr) * LDA + q * 8;
    #pragma unroll
    for (int ni = 0; ni < 4; ++ni) offB[ni] = (wn + ni * 16 + fr) * LDA + q * 8;

    f32x4 acc[4][4] = {};

#define COMPUTE(BUF) {                                                        \
        short8 bf[4];                                                         \
        _Pragma("unroll")                                                     \
        for (int ni = 0; ni < 4; ++ni)                                        \
            bf[ni] = *(const short8*)&lB[BUF][offB[ni]];                      \
        _Pragma("unroll")                                                     \
        for (int mi = 0; mi < 4; ++mi) {                                      \
            short8 af = *(const short8*)&lA[BUF][offA[mi]];                   \
            _Pragma("unroll")                                                 \
            for (int ni = 0; ni < 4; ++ni)                                    \
                acc[mi][ni] = __builtin_amdgcn_mfma_f32_16x16x32_bf16(        \
                    af, bf[ni], acc[mi][ni], 0, 0, 0);                        \
        }                                                                     \
    }

    STAGE(0, 0);
    __syncthreads();
    #pragma unroll
    for (int t = 0; t < KITERS; ++t) {
        COMPUTE(t & 1);
        if (t + 1 < KITERS) STAGE((t + 1) & 1, t + 1);   // writes other buffer
        __syncthreads();
    }
#undef STAGE
#undef COMPUTE

    // ---- epilogue. C/D 16x16x32: col = fr, row = q*4 + j.
    if (USE_WS) {
        // permuted cols within each 64-col wave region: colp = fr*4 + ni
        // (true col = ni*16 + fr); reduce kernel inverts.
        unsigned short* slice = wsb + (size_t)kb * SLICE_ELEMS;
        const int pbase = bn + wn + fr * 4;
        #pragma unroll
        for (int mi = 0; mi < 4; ++mi) {
            #pragma unroll
            for (int j = 0; j < 4; ++j) {
                const int r = wm + mi * 16 + q * 4 + j;
                u16x4 v;
                #pragma unroll
                for (int ni = 0; ni < 4; ++ni) v[ni] = f2bf(acc[mi][ni][j]);
                *(u16x4*)&slice[(size_t)r * CO + pbase] = v;
            }
        }
    } else {
        #pragma unroll
        for (int mi = 0; mi < 4; ++mi)
            #pragma unroll
            for (int ni = 0; ni < 4; ++ni) {
                const int col = bn + wn + ni * 16 + fr;
                #pragma unroll
                for (int j = 0; j < 4; ++j) {
                    const int r = wm + mi * 16 + q * 4 + j;
                    unsafeAtomicAdd(out + (size_t)r * CO + col, acc[mi][ni][j]);
                }
            }
    }
}

// sum 64 bf16 slices elementwise and invert the column permutation.
// group g (u16x4): r = g>>8, p = g&255, c64 = p>>4, L = p&15;
// element e -> out col = c64*64 + e*16 + L.
__global__ __launch_bounds__(256)
void reduce_splitk_v8(const unsigned short* __restrict__ ws, float* __restrict__ out) {
    const int g = blockIdx.x * 256 + threadIdx.x;    // 0 .. 65535
    const u16x4* base = (const u16x4*)ws;
    float s[4] = {0, 0, 0, 0};
    #pragma unroll 8
    for (int sdx = 0; sdx < SKB; ++sdx) {
        u16x4 v = base[(size_t)sdx * (SLICE_ELEMS / 4) + g];
        #pragma unroll
        for (int e = 0; e < 4; ++e) {
            unsigned int u = ((unsigned int)v[e]) << 16;
            s[e] += __builtin_bit_cast(float, u);
        }
    }
    const int r   = g >> 8;
    const int p   = g & 255;
    const int c64 = p >> 4;
    const int L   = p & 15;
    float* orow = out + (size_t)r * CO + c64 * 64 + L;
    #pragma unroll
    for (int e = 0; e < 4; ++e) orow[e * 16] = s[e];
}

extern "C" void kernel_launch(void* const* d_in, const int* in_sizes, int n_in,
                              void* d_out, int out_size, void* d_ws, size_t ws_size,
                              hipStream_t stream) {
    const float* A = (const float*)d_in[0];
    const float* W = (const float*)d_in[1];
    float* out = (float*)d_out;
    unsigned short* ws = (unsigned short*)d_ws;

    const size_t ws_needed = (size_t)SKB * SLICE_ELEMS * sizeof(unsigned short); // 33.5 MB

    if (ws_size >= ws_needed) {
        sconv_gemm_v8<true><<<NB * SKB, 512, 0, stream>>>(A, W, out, ws);
        reduce_splitk_v8<<<SLICE_ELEMS / 4 / 256, 256, 0, stream>>>(ws, out);
    } else {
        hipMemsetAsync(d_out, 0, (size_t)out_size * sizeof(float), stream);
        sconv_gemm_v8<false><<<NB * SKB, 512, 0, stream>>>(A, W, out, ws);
    }
}